// Round 3
// baseline (276.628 us; speedup 1.0000x reference)
//
#include <hip/hip_runtime.h>
#include <math.h>

#define PI_F   3.14159265358979f
#define STRIDE 66     // f2 slots per 64-amp row (64 + 2 pad) -> 528B row stride
#define PADF2  32     // 256B front pad so chain-gather va1 base stays >= 0

typedef __attribute__((ext_vector_type(2))) float f2;
typedef __attribute__((ext_vector_type(4))) float f4;

// Apply 6 single-qubit gates to the 64 in-register amps.
// Register-bit k of index r corresponds to wire (wbase - k).
// Us[w] = {r00,i00,r01,i01,r10,i10,r11,i11} for wire w.
__device__ __forceinline__ void apply6(f2 (&cA)[64], const float (*Us)[8], const int wbase)
{
    #pragma unroll
    for (int k = 0; k < 6; ++k) {
        const float* u = Us[wbase - k];
        const float u0 = u[0], u1 = u[1], u2 = u[2], u3 = u[3];
        const float u4 = u[4], u5 = u[5], u6 = u[6], u7 = u[7];
        const f2 n1 = {-u1, u1}, n3 = {-u3, u3}, n5 = {-u5, u5}, n7 = {-u7, u7};
        #pragma unroll
        for (int h = 0; h < 32; ++h) {
            const int r0 = ((h >> k) << (k + 1)) | (h & ((1 << k) - 1));
            const int r1 = r0 | (1 << k);
            const f2 a = cA[r0], b = cA[r1];
            const f2 ay = {a.y, a.x}, by = {b.y, b.x};
            f2 na = u0 * a;  na += n1 * ay;  na += u2 * b;  na += n3 * by;
            f2 nb = u4 * a;  nb += n5 * ay;  nb += u6 * b;  nb += n7 * by;
            cA[r0] = na;  cA[r1] = nb;
        }
    }
}

extern "C" __global__ void __launch_bounds__(64, 1)
qsim_kernel(const float* __restrict__ x, const float* __restrict__ Wp,
            const float* __restrict__ bp, const float* __restrict__ w,
            const float* __restrict__ scal, float* __restrict__ out)
{
    __shared__ __align__(16) f2 sSt[PADF2 + STRIDE * 64];   // 34048 B
    __shared__ float sU[5][12][8];
    __shared__ float sXq[12];

    const int l = threadIdx.x;   // 64 lanes = 1 wave = 1 sample
    const int b = blockIdx.x;

    // ---------------- projection: xq[q] = tanh(x.W[q]+b[q])*pi ----------------
    const f4 xv = ((const f4*)x)[(size_t)b * 64 + l];
    float nrm = 1e-10f;
    #pragma unroll
    for (int q = 0; q < 12; ++q) {
        const f4 wv = ((const f4*)Wp)[q * 64 + l];
        float acc = xv.x * wv.x;
        acc = fmaf(xv.y, wv.y, acc);
        acc = fmaf(xv.z, wv.z, acc);
        acc = fmaf(xv.w, wv.w, acc);
        acc += __shfl_xor(acc, 1);  acc += __shfl_xor(acc, 2);
        acc += __shfl_xor(acc, 4);  acc += __shfl_xor(acc, 8);
        acc += __shfl_xor(acc, 16); acc += __shfl_xor(acc, 32);
        const float xq = tanhf(acc + bp[q]) * PI_F;   // uniform across lanes
        if (l == 0) sXq[q] = xq;
        nrm = fmaf(xq, xq, nrm);
    }
    const float einv = PI_F * rsqrtf(nrm);            // uniform

    // ---------------- init state |0...0> in LDS (standard layout) ----------------
    {
        const f4 z = {0.f, 0.f, 0.f, 0.f};
        f4* row = (f4*)&sSt[PADF2 + STRIDE * l];
        #pragma unroll
        for (int j = 0; j < 32; ++j) row[j] = z;
        if (l == 0) sSt[PADF2] = f2{1.f, 0.f};
    }

    // ---------------- build 60 fused per-wire unitaries ----------------
    // sweep 0 = Rz*Ry*Rx*Ry_enc, sweeps 1..3 = Rz*Ry*Rx, sweep 4 = final RY
    if (l < 60) {
        const int s_ = l / 12, q = l - s_ * 12;
        float U[8];
        if (s_ == 4) {
            float c, s; sincosf(0.5f * w[144 + q], &s, &c);
            U[0] = c;  U[1] = 0.f; U[2] = -s; U[3] = 0.f;
            U[4] = s;  U[5] = 0.f; U[6] = c;  U[7] = 0.f;
        } else {
            const float sc = scal[s_];
            const float hx = 0.5f * sc * w[s_ * 36 + q];
            const float hy = 0.5f * sc * w[s_ * 36 + 12 + q];
            const float hz = 0.5f * sc * w[s_ * 36 + 24 + q];
            float cx, sx, cy, sy, cz, sz;
            sincosf(hx, &sx, &cx); sincosf(hy, &sy, &cy); sincosf(hz, &sz, &cz);
            const float T00r = cy * cx, T00i =  sy * sx;
            const float T01r = -sy * cx, T01i = -cy * sx;
            const float T10r =  sy * cx, T10i = -cy * sx;
            const float T11r =  cy * cx, T11i = -sy * sx;
            U[0] = cz * T00r + sz * T00i;  U[1] = cz * T00i - sz * T00r;
            U[2] = cz * T01r + sz * T01i;  U[3] = cz * T01i - sz * T01r;
            U[4] = cz * T10r - sz * T10i;  U[5] = cz * T10i + sz * T10r;
            U[6] = cz * T11r - sz * T11i;  U[7] = cz * T11i + sz * T11r;
            if (s_ == 0) {   // right-multiply by encoding RY (applied first)
                float ce, se; sincosf(0.5f * sXq[q] * einv, &se, &ce);
                const float r00 = U[0]*ce + U[2]*se, i00 = U[1]*ce + U[3]*se;
                const float r01 = U[2]*ce - U[0]*se, i01 = U[3]*ce - U[1]*se;
                const float r10 = U[4]*ce + U[6]*se, i10 = U[5]*ce + U[7]*se;
                const float r11 = U[6]*ce - U[4]*se, i11 = U[7]*ce - U[5]*se;
                U[0]=r00; U[1]=i00; U[2]=r01; U[3]=i01;
                U[4]=r10; U[5]=i10; U[6]=r11; U[7]=i11;
            }
        }
        *(f4*)&sU[s_][q][0] = f4{U[0], U[1], U[2], U[3]};
        *(f4*)&sU[s_][q][4] = f4{U[4], U[5], U[6], U[7]};
    }

    // ---------------- main loop: 5 sweeps x (P0 + P1) ----------------
    // P0: thread holds v = (l<<6)|r  (bits 5..0 in-register -> wires 11..6)
    // P1: thread holds v = (r<<6)|l  (bits 11..6 in-register -> wires 5..0)
    // CNOT chain perm new[v] = old[v ^ (v>>1)] fused into the P0 gather.
    // |0> is invariant under the chain, so sweep 0 uses the same gather.
    f2 cA[64];
    const int G    = l ^ (l >> 1);                 // Gray(l) = hi bits of source
    const int rb   = PADF2 * 8 + 528 * G;          // byte rowbase of source row
    const int bsel = (l & 1) << 8;                 // 256 * (l&1): lo-bit5 flip
    char* const ldsB = (char*)&sSt[0];
    const char* const va0 = ldsB + rb + bsel;      // chunks with pm bit5 == 0
    const char* const va1 = ldsB + rb - bsel;      // chunks with pm bit5 == 1
    f4* const rowP0 = (f4*)&sSt[PADF2 + STRIDE * l];
    f2* const colP1 = &sSt[PADF2 + l];

    for (int s = 0; s < 5; ++s) {
        // ---- P0 gather with fused chain perm (Gray-code pair reads) ----
        #pragma unroll
        for (int m = 0; m < 32; ++m) {
            const int gm = (2 * m) ^ m;            // f(2m), compile-time
            const int pm = gm & ~1;                // pair base slot
            const char* base = (pm & 32) ? va1 : va0;
            const f4 D = *(const f4*)(base + 8 * pm);
            if (m & 1) { cA[2*m] = f2{D.z, D.w}; cA[2*m + 1] = f2{D.x, D.y}; }
            else       { cA[2*m] = f2{D.x, D.y}; cA[2*m + 1] = f2{D.z, D.w}; }
        }
        apply6(cA, sU[s], 11);                     // wires 11..6

        // ---- P0 scatter (contiguous b128, own row) ----
        #pragma unroll
        for (int j = 0; j < 32; ++j)
            rowP0[j] = f4{cA[2*j].x, cA[2*j].y, cA[2*j + 1].x, cA[2*j + 1].y};

        // ---- P1 gather (transpose: column reads, b64) ----
        #pragma unroll
        for (int r = 0; r < 64; ++r)
            cA[r] = colP1[STRIDE * r];
        apply6(cA, sU[s], 5);                      // wires 5..0

        // ---- P1 scatter (skip after last sweep: measure from registers) ----
        if (s < 4) {
            #pragma unroll
            for (int r = 0; r < 64; ++r)
                colP1[STRIDE * r] = cA[r];
        }
    }

    // ---------------- measurement: lane holds v = (r<<6)|l ----------------
    // wire q in 0..5  <-> r-bit (5-q);  wire q in 6..11 <-> l-bit (11-q)
    float zq0 = 0.f, zq1 = 0.f, zq2 = 0.f, zq3 = 0.f, zq4 = 0.f, zq5 = 0.f, zt = 0.f;
    #pragma unroll
    for (int r = 0; r < 64; ++r) {
        const f2 a = cA[r];
        const float p = fmaf(a.x, a.x, a.y * a.y);
        zt += p;
        zq0 += (r & 32) ? -p : p;
        zq1 += (r & 16) ? -p : p;
        zq2 += (r & 8)  ? -p : p;
        zq3 += (r & 4)  ? -p : p;
        zq4 += (r & 2)  ? -p : p;
        zq5 += (r & 1)  ? -p : p;
    }
    float Z[12];
    {
        float v;
        v = zq0; v += __shfl_xor(v,1); v += __shfl_xor(v,2); v += __shfl_xor(v,4);
                 v += __shfl_xor(v,8); v += __shfl_xor(v,16); v += __shfl_xor(v,32); Z[0] = v;
        v = zq1; v += __shfl_xor(v,1); v += __shfl_xor(v,2); v += __shfl_xor(v,4);
                 v += __shfl_xor(v,8); v += __shfl_xor(v,16); v += __shfl_xor(v,32); Z[1] = v;
        v = zq2; v += __shfl_xor(v,1); v += __shfl_xor(v,2); v += __shfl_xor(v,4);
                 v += __shfl_xor(v,8); v += __shfl_xor(v,16); v += __shfl_xor(v,32); Z[2] = v;
        v = zq3; v += __shfl_xor(v,1); v += __shfl_xor(v,2); v += __shfl_xor(v,4);
                 v += __shfl_xor(v,8); v += __shfl_xor(v,16); v += __shfl_xor(v,32); Z[3] = v;
        v = zq4; v += __shfl_xor(v,1); v += __shfl_xor(v,2); v += __shfl_xor(v,4);
                 v += __shfl_xor(v,8); v += __shfl_xor(v,16); v += __shfl_xor(v,32); Z[4] = v;
        v = zq5; v += __shfl_xor(v,1); v += __shfl_xor(v,2); v += __shfl_xor(v,4);
                 v += __shfl_xor(v,8); v += __shfl_xor(v,16); v += __shfl_xor(v,32); Z[5] = v;
    }
    #pragma unroll
    for (int q = 6; q < 12; ++q) {
        const int bit = 11 - q;
        float v = ((l >> bit) & 1) ? -zt : zt;
        v += __shfl_xor(v,1); v += __shfl_xor(v,2); v += __shfl_xor(v,4);
        v += __shfl_xor(v,8); v += __shfl_xor(v,16); v += __shfl_xor(v,32);
        Z[q] = v;
    }
    if (l == 0) {
        float* o = out + (size_t)b * 12;
        *(f4*)&o[0] = f4{Z[0], Z[1], Z[2],  Z[3]};
        *(f4*)&o[4] = f4{Z[4], Z[5], Z[6],  Z[7]};
        *(f4*)&o[8] = f4{Z[8], Z[9], Z[10], Z[11]};
    }
}

extern "C" void kernel_launch(void* const* d_in, const int* in_sizes, int n_in,
                              void* d_out, int out_size, void* d_ws, size_t ws_size,
                              hipStream_t stream) {
    const float* x    = (const float*)d_in[0];
    const float* Wp   = (const float*)d_in[1];
    const float* bp   = (const float*)d_in[2];
    const float* w    = (const float*)d_in[3];
    const float* scal = (const float*)d_in[4];
    float* outp = (float*)d_out;
    hipLaunchKernelGGL(qsim_kernel, dim3(4096), dim3(64), 0, stream,
                       x, Wp, bp, w, scal, outp);
}

// Round 5
// 236.058 us; speedup vs baseline: 1.1719x; 1.1719x over previous
//
#include <hip/hip_runtime.h>
#include <math.h>

#define NQ   12
#define DIM  4096
#define PI_F 3.14159265358979f

typedef __attribute__((ext_vector_type(2))) float f2;
typedef __attribute__((ext_vector_type(4))) float f4;

// slot swizzle: XOR bits 1..3 with bits 5..7 (bijective; scatter/gather bank-optimal)
__device__ __forceinline__ int swz(int v) { return v ^ (((v >> 5) & 7) << 1); }

// complex 2x2 gate on amp pair (a = wire-bit 0, b = wire-bit 1), AoS f2 = {re, im}.
// coeffs: c*r = {r,r}, c*i = {-i,+i}. op_sel:[0,1,0] op_sel_hi:[1,0,1] swaps src1 halves:
//   lo += c.lo * src.hi   (-i * im)      hi += c.hi * src.lo   (+i * re)
__device__ __forceinline__ void cgate(f2 &a, f2 &b,
    f2 c0r, f2 c0i, f2 c1r, f2 c1i, f2 c2r, f2 c2i, f2 c3r, f2 c3i)
{
    f2 na, nb;
    asm("v_pk_mul_f32 %0, %1, %2" : "=v"(na) : "v"(c0r), "v"(a));
    asm("v_pk_fma_f32 %0, %1, %2, %0 op_sel:[0,1,0] op_sel_hi:[1,0,1]"
        : "+v"(na) : "v"(c0i), "v"(a));
    asm("v_pk_fma_f32 %0, %1, %2, %0" : "+v"(na) : "v"(c1r), "v"(b));
    asm("v_pk_fma_f32 %0, %1, %2, %0 op_sel:[0,1,0] op_sel_hi:[1,0,1]"
        : "+v"(na) : "v"(c1i), "v"(b));
    asm("v_pk_mul_f32 %0, %1, %2" : "=v"(nb) : "v"(c2r), "v"(a));
    asm("v_pk_fma_f32 %0, %1, %2, %0 op_sel:[0,1,0] op_sel_hi:[1,0,1]"
        : "+v"(nb) : "v"(c2i), "v"(a));
    asm("v_pk_fma_f32 %0, %1, %2, %0" : "+v"(nb) : "v"(c3r), "v"(b));
    asm("v_pk_fma_f32 %0, %1, %2, %0 op_sel:[0,1,0] op_sel_hi:[1,0,1]"
        : "+v"(nb) : "v"(c3i), "v"(b));
    a = na; b = nb;
}

__device__ __forceinline__ float wred(float v) {
    v += __shfl_xor(v, 1);  v += __shfl_xor(v, 2);  v += __shfl_xor(v, 4);
    v += __shfl_xor(v, 8);  v += __shfl_xor(v, 16); v += __shfl_xor(v, 32);
    return v;
}

extern "C" __global__ void __launch_bounds__(256, 4)
qsim_kernel(const float* __restrict__ x, const float* __restrict__ Wp,
            const float* __restrict__ bp, const float* __restrict__ w,
            const float* __restrict__ scal, float* __restrict__ out)
{
    __shared__ __align__(16) f2 sSt[DIM];       // AoS state: slot -> {re, im}; 32 KB
    __shared__ __align__(16) f2 sU2[5][NQ][8];  // asm-ready coeff pairs; 3840 B
    __shared__ float sXq[NQ];
    __shared__ float sRed[4][NQ];

    const int t = threadIdx.x;
    const int b = blockIdx.x;

    // ---- zero state + |0...0> (swz(0)==0, written by t==0 after its own zero) ----
    {
        const f4 z = {0.f, 0.f, 0.f, 0.f};
        #pragma unroll
        for (int k = 0; k < 8; ++k) ((f4*)sSt)[t + (k << 8)] = z;
        if (t == 0) sSt[0] = f2{1.f, 0.f};
    }

    // ---- projection: xq[q] = tanh(x.W[q] + b[q]) * pi ----
    {
        const int q = t >> 4, h = t & 15;
        if (q < NQ) {
            const float* xr = x + (size_t)b * 256;
            const float* wr = Wp + q * 256;
            float acc = 0.f;
            #pragma unroll
            for (int m2 = 0; m2 < 16; ++m2) {
                const int f = h + (m2 << 4);
                acc = fmaf(xr[f], wr[f], acc);
            }
            acc += __shfl_xor(acc, 1);
            acc += __shfl_xor(acc, 2);
            acc += __shfl_xor(acc, 4);
            acc += __shfl_xor(acc, 8);
            if (h == 0) sXq[q] = tanhf(acc + bp[q]) * PI_F;
        }
    }
    __syncthreads();

    // ---- build 60 fused per-wire unitaries (asm-ready pair layout) ----
    if (t < 60) {
        const int s_ = t / 12, q = t - s_ * 12;
        float U[8];
        if (s_ == 4) {
            float c, s; sincosf(0.5f * w[144 + q], &s, &c);
            U[0] = c;  U[1] = 0.f; U[2] = -s; U[3] = 0.f;
            U[4] = s;  U[5] = 0.f; U[6] = c;  U[7] = 0.f;
        } else {
            const float sc = scal[s_];
            const float hx = 0.5f * sc * w[s_ * 36 + q];
            const float hy = 0.5f * sc * w[s_ * 36 + 12 + q];
            const float hz = 0.5f * sc * w[s_ * 36 + 24 + q];
            float cx, sx, cy, sy, cz, sz;
            sincosf(hx, &sx, &cx); sincosf(hy, &sy, &cy); sincosf(hz, &sz, &cz);
            const float T00r = cy * cx, T00i =  sy * sx;
            const float T01r = -sy * cx, T01i = -cy * sx;
            const float T10r =  sy * cx, T10i = -cy * sx;
            const float T11r =  cy * cx, T11i = -sy * sx;
            U[0] = cz * T00r + sz * T00i;  U[1] = cz * T00i - sz * T00r;
            U[2] = cz * T01r + sz * T01i;  U[3] = cz * T01i - sz * T01r;
            U[4] = cz * T10r - sz * T10i;  U[5] = cz * T10i + sz * T10r;
            U[6] = cz * T11r - sz * T11i;  U[7] = cz * T11i + sz * T11r;
            if (s_ == 0) {   // right-multiply by encoding RY (applied first)
                float nrm = 1e-10f;
                #pragma unroll
                for (int k2 = 0; k2 < NQ; ++k2) nrm += sXq[k2] * sXq[k2];
                const float einv = PI_F * rsqrtf(nrm);
                float ce, se; sincosf(0.5f * sXq[q] * einv, &se, &ce);
                const float r00 = U[0]*ce + U[2]*se, i00 = U[1]*ce + U[3]*se;
                const float r01 = U[2]*ce - U[0]*se, i01 = U[3]*ce - U[1]*se;
                const float r10 = U[4]*ce + U[6]*se, i10 = U[5]*ce + U[7]*se;
                const float r11 = U[6]*ce - U[4]*se, i11 = U[7]*ce - U[5]*se;
                U[0]=r00; U[1]=i00; U[2]=r01; U[3]=i01;
                U[4]=r10; U[5]=i10; U[6]=r11; U[7]=i11;
            }
        }
        sU2[s_][q][0] = f2{ U[0], U[0] };  sU2[s_][q][1] = f2{ -U[1], U[1] };
        sU2[s_][q][2] = f2{ U[2], U[2] };  sU2[s_][q][3] = f2{ -U[3], U[3] };
        sU2[s_][q][4] = f2{ U[4], U[4] };  sU2[s_][q][5] = f2{ -U[5], U[5] };
        sU2[s_][q][6] = f2{ U[6], U[6] };  sU2[s_][q][7] = f2{ -U[7], U[7] };
    }

    // ---- hoisted addresses ----
    const int tx    = t ^ (((t >> 5) & 7) << 1);        // gather base (swizzled)
    const char* const gbase = (const char*)sSt + (tx << 3);
    const int W = (t << 7) | (((t >> 1) & 7) << 4);     // scatter base | swizzle-xor
    char* const ldsB = (char*)sSt;
    __syncthreads();

    // ---- 15 passes: 5 sweeps x 3 rot-4 passes; 4 in-register wires each.
    //      CNOT chain (v ^= v>>1 source perm) fused into gather of pass 0, sweeps>0. ----
    f2 cA[16];
    for (int s = 0; s < 5; ++s) {
        #pragma unroll
        for (int p = 0; p < 3; ++p) {
            if (p == 0 && s > 0) {
                #pragma unroll
                for (int j = 0; j < 16; ++j) {
                    int v = (j << 8) | t;
                    v ^= (v >> 1);
                    cA[j] = *(const f2*)(ldsB + (swz(v) << 3));
                }
            } else {
                #pragma unroll
                for (int j = 0; j < 16; ++j)
                    cA[j] = *(const f2*)(gbase + (j << 11));
            }

            // 4 wires: register j-bit (3-g) <-> wire 4p+g
            #pragma unroll
            for (int g = 0; g < 4; ++g) {
                const f2* cw = sU2[s][4 * p + g];
                const f2 c0r = cw[0], c0i = cw[1], c1r = cw[2], c1i = cw[3];
                const f2 c2r = cw[4], c2i = cw[5], c3r = cw[6], c3i = cw[7];
                #pragma unroll
                for (int m = 0; m < 8; ++m) {
                    const int r0 = ((m >> (3 - g)) << (4 - g)) | (m & ((1 << (3 - g)) - 1));
                    const int r1 = r0 | (8 >> g);
                    cgate(cA[r0], cA[r1], c0r, c0i, c1r, c1i, c2r, c2i, c3r, c3i);
                }
            }

            if (!(s == 4 && p == 2)) {
                __syncthreads();     // all gathers done before in-place scatter
                #pragma unroll
                for (int k = 0; k < 8; ++k) {
                    const f4 vv = {cA[2*k].x, cA[2*k].y, cA[2*k+1].x, cA[2*k+1].y};
                    *(f4*)(ldsB + (W ^ (k << 4))) = vv;
                }
                __syncthreads();
            }
        }
    }

    // ---- measurement from registers: lane t register j holds amp v=(t<<4)|j ----
    // wire 0 <-> t7, wire 1 <-> t6, wires 2..7 <-> t5..t0, wires 8..11 <-> j3..j0
    float zt = 0.f, z8 = 0.f, z9 = 0.f, z10 = 0.f, z11 = 0.f;
    #pragma unroll
    for (int j = 0; j < 16; ++j) {
        const f2 a = cA[j];
        const float pv = fmaf(a.x, a.x, a.y * a.y);
        zt  += pv;
        z8  += (j & 8) ? -pv : pv;
        z9  += (j & 4) ? -pv : pv;
        z10 += (j & 2) ? -pv : pv;
        z11 += (j & 1) ? -pv : pv;
    }
    const int l = t & 63, wv = t >> 6;
    float R[NQ];
    R[0] = wred(zt);                                   // per-wave total (signs at combine)
    #pragma unroll
    for (int q = 2; q < 8; ++q)
        R[q] = wred(((l >> (7 - q)) & 1) ? -zt : zt);
    R[8] = wred(z8); R[9] = wred(z9); R[10] = wred(z10); R[11] = wred(z11);
    if (l == 0) {
        sRed[wv][0] = R[0];
        #pragma unroll
        for (int q = 2; q < 12; ++q) sRed[wv][q] = R[q];
    }
    __syncthreads();
    if (t < NQ) {
        float v;
        if (t >= 2)      v = sRed[0][t] + sRed[1][t] + sRed[2][t] + sRed[3][t];
        else if (t == 0) v = sRed[0][0] + sRed[1][0] - sRed[2][0] - sRed[3][0];  // w-bit1
        else             v = sRed[0][0] - sRed[1][0] + sRed[2][0] - sRed[3][0];  // w-bit0
        out[(size_t)b * NQ + t] = v;
    }
}

extern "C" void kernel_launch(void* const* d_in, const int* in_sizes, int n_in,
                              void* d_out, int out_size, void* d_ws, size_t ws_size,
                              hipStream_t stream) {
    const float* x    = (const float*)d_in[0];
    const float* Wp   = (const float*)d_in[1];
    const float* bp   = (const float*)d_in[2];
    const float* w    = (const float*)d_in[3];
    const float* scal = (const float*)d_in[4];
    float* outp = (float*)d_out;
    hipLaunchKernelGGL(qsim_kernel, dim3(4096), dim3(256), 0, stream,
                       x, Wp, bp, w, scal, outp);
}

// Round 6
// 229.286 us; speedup vs baseline: 1.2065x; 1.0295x over previous
//
#include <hip/hip_runtime.h>
#include <hip/hip_fp16.h>
#include <math.h>

#define NQ   12
#define DIM  4096
#define PI_F 3.14159265358979f

typedef __attribute__((ext_vector_type(2))) float f2;
typedef __attribute__((ext_vector_type(4))) float f4;
typedef __attribute__((ext_vector_type(4))) unsigned int u4;

// complex 2x2 gate on amp pair (a = wire-bit 0, b = wire-bit 1), f2 = {re, im}.
// coeffs: c*r = {r,r}, c*i = {-i,+i}. op_sel:[0,1,0] op_sel_hi:[1,0,1] swaps src1 halves.
__device__ __forceinline__ void cgate(f2 &a, f2 &b,
    f2 c0r, f2 c0i, f2 c1r, f2 c1i, f2 c2r, f2 c2i, f2 c3r, f2 c3i)
{
    f2 na, nb;
    asm("v_pk_mul_f32 %0, %1, %2" : "=v"(na) : "v"(c0r), "v"(a));
    asm("v_pk_fma_f32 %0, %1, %2, %0 op_sel:[0,1,0] op_sel_hi:[1,0,1]"
        : "+v"(na) : "v"(c0i), "v"(a));
    asm("v_pk_fma_f32 %0, %1, %2, %0" : "+v"(na) : "v"(c1r), "v"(b));
    asm("v_pk_fma_f32 %0, %1, %2, %0 op_sel:[0,1,0] op_sel_hi:[1,0,1]"
        : "+v"(na) : "v"(c1i), "v"(b));
    asm("v_pk_mul_f32 %0, %1, %2" : "=v"(nb) : "v"(c2r), "v"(a));
    asm("v_pk_fma_f32 %0, %1, %2, %0 op_sel:[0,1,0] op_sel_hi:[1,0,1]"
        : "+v"(nb) : "v"(c2i), "v"(a));
    asm("v_pk_fma_f32 %0, %1, %2, %0" : "+v"(nb) : "v"(c3r), "v"(b));
    asm("v_pk_fma_f32 %0, %1, %2, %0 op_sel:[0,1,0] op_sel_hi:[1,0,1]"
        : "+v"(nb) : "v"(c3i), "v"(b));
    a = na; b = nb;
}

__device__ __forceinline__ float wred(float v) {
    v += __shfl_xor(v, 1);  v += __shfl_xor(v, 2);  v += __shfl_xor(v, 4);
    v += __shfl_xor(v, 8);  v += __shfl_xor(v, 16); v += __shfl_xor(v, 32);
    return v;
}

extern "C" __global__ void __launch_bounds__(256, 4)
qsim_kernel(const float* __restrict__ x, const float* __restrict__ Wp,
            const float* __restrict__ bp, const float* __restrict__ w,
            const float* __restrict__ scal, float* __restrict__ out)
{
    // fp16 AoS state (u32 = packed {re,im} f16), double-buffered ping-pong
    __shared__ __align__(16) unsigned int sA[DIM];   // 16 KB
    __shared__ __align__(16) unsigned int sB[DIM];   // 16 KB
    __shared__ __align__(16) f2 sU2[5][NQ][8];       // asm-ready coeff pairs
    __shared__ float sXq[NQ];
    __shared__ float sRed[4][NQ];

    const int t = threadIdx.x;
    const int b = blockIdx.x;

    // ---- zero state + |0...0> (swz(0)==0; t==0 owns slots 0..3) ----
    {
        const u4 z = {0u, 0u, 0u, 0u};
        #pragma unroll
        for (int k = 0; k < 4; ++k) ((u4*)sA)[t + (k << 8)] = z;
        if (t == 0) sA[0] = 0x3C00u;    // f16 {re=1.0, im=0}
    }

    // ---- projection: xq[q] = tanh(x.W[q] + b[q]) * pi ----
    {
        const int q = t >> 4, h = t & 15;
        if (q < NQ) {
            const float* xr = x + (size_t)b * 256;
            const float* wr = Wp + q * 256;
            float acc = 0.f;
            #pragma unroll
            for (int m2 = 0; m2 < 16; ++m2) {
                const int f = h + (m2 << 4);
                acc = fmaf(xr[f], wr[f], acc);
            }
            acc += __shfl_xor(acc, 1);
            acc += __shfl_xor(acc, 2);
            acc += __shfl_xor(acc, 4);
            acc += __shfl_xor(acc, 8);
            if (h == 0) sXq[q] = tanhf(acc + bp[q]) * PI_F;
        }
    }
    __syncthreads();

    // ---- build 60 fused per-wire unitaries (asm-ready pair layout) ----
    if (t < 60) {
        const int s_ = t / 12, q = t - s_ * 12;
        float U[8];
        if (s_ == 4) {
            float c, s; sincosf(0.5f * w[144 + q], &s, &c);
            U[0] = c;  U[1] = 0.f; U[2] = -s; U[3] = 0.f;
            U[4] = s;  U[5] = 0.f; U[6] = c;  U[7] = 0.f;
        } else {
            const float sc = scal[s_];
            const float hx = 0.5f * sc * w[s_ * 36 + q];
            const float hy = 0.5f * sc * w[s_ * 36 + 12 + q];
            const float hz = 0.5f * sc * w[s_ * 36 + 24 + q];
            float cx, sx, cy, sy, cz, sz;
            sincosf(hx, &sx, &cx); sincosf(hy, &sy, &cy); sincosf(hz, &sz, &cz);
            const float T00r = cy * cx, T00i =  sy * sx;
            const float T01r = -sy * cx, T01i = -cy * sx;
            const float T10r =  sy * cx, T10i = -cy * sx;
            const float T11r =  cy * cx, T11i = -sy * sx;
            U[0] = cz * T00r + sz * T00i;  U[1] = cz * T00i - sz * T00r;
            U[2] = cz * T01r + sz * T01i;  U[3] = cz * T01i - sz * T01r;
            U[4] = cz * T10r - sz * T10i;  U[5] = cz * T10i + sz * T10r;
            U[6] = cz * T11r - sz * T11i;  U[7] = cz * T11i + sz * T11r;
            if (s_ == 0) {   // right-multiply by encoding RY (applied first)
                float nrm = 1e-10f;
                #pragma unroll
                for (int k2 = 0; k2 < NQ; ++k2) nrm += sXq[k2] * sXq[k2];
                const float einv = PI_F * rsqrtf(nrm);
                float ce, se; sincosf(0.5f * sXq[q] * einv, &se, &ce);
                const float r00 = U[0]*ce + U[2]*se, i00 = U[1]*ce + U[3]*se;
                const float r01 = U[2]*ce - U[0]*se, i01 = U[3]*ce - U[1]*se;
                const float r10 = U[4]*ce + U[6]*se, i10 = U[5]*ce + U[7]*se;
                const float r11 = U[6]*ce - U[4]*se, i11 = U[7]*ce - U[5]*se;
                U[0]=r00; U[1]=i00; U[2]=r01; U[3]=i01;
                U[4]=r10; U[5]=i10; U[6]=r11; U[7]=i11;
            }
        }
        sU2[s_][q][0] = f2{ U[0], U[0] };  sU2[s_][q][1] = f2{ -U[1], U[1] };
        sU2[s_][q][2] = f2{ U[2], U[2] };  sU2[s_][q][3] = f2{ -U[3], U[3] };
        sU2[s_][q][4] = f2{ U[4], U[4] };  sU2[s_][q][5] = f2{ -U[5], U[5] };
        sU2[s_][q][6] = f2{ U[6], U[6] };  sU2[s_][q][7] = f2{ -U[7], U[7] };
    }

    // ---- hoisted addresses (slot swizzle: bits 2..4 ^= bits 5..7; line-preserving) ----
    const int tx2 = t ^ (((t >> 5) & 7) << 2);            // gather slot base
    const int wb  = (t << 4) ^ (((t >> 1) & 7) << 2);     // scatter slot base (b128 lines)
    __syncthreads();

    // ---- 15 passes: 5 sweeps x 3 rot-4 passes; ping-pong, ONE barrier per pass.
    //      CNOT chain (v ^= v>>1 source perm) fused into gather of pass 0, sweeps>0. ----
    f2 cA[16];
    for (int s = 0; s < 5; ++s) {
        #pragma unroll
        for (int p = 0; p < 3; ++p) {
            const int pp = 3 * s + p;
            const unsigned int* bufR = (pp & 1) ? sB : sA;
            unsigned int*       bufW = (pp & 1) ? sA : sB;

            unsigned int g[16];
            if (p == 0 && s > 0) {
                #pragma unroll
                for (int j = 0; j < 16; ++j) {
                    int v = (j << 8) | t;
                    v ^= (v >> 1);
                    g[j] = bufR[v ^ (((v >> 5) & 7) << 2)];
                }
            } else {
                #pragma unroll
                for (int j = 0; j < 16; ++j)
                    g[j] = bufR[(j << 8) | tx2];
            }
            #pragma unroll
            for (int j = 0; j < 16; ++j) {
                const float2 fv = __half22float2(*(const __half2*)&g[j]);
                cA[j] = f2{fv.x, fv.y};
            }

            // 4 wires: register j-bit (3-gw) <-> wire 4p+gw
            #pragma unroll
            for (int gw = 0; gw < 4; ++gw) {
                const f2* cw = sU2[s][4 * p + gw];
                const f2 c0r = cw[0], c0i = cw[1], c1r = cw[2], c1i = cw[3];
                const f2 c2r = cw[4], c2i = cw[5], c3r = cw[6], c3i = cw[7];
                #pragma unroll
                for (int m = 0; m < 8; ++m) {
                    const int r0 = ((m >> (3 - gw)) << (4 - gw)) | (m & ((1 << (3 - gw)) - 1));
                    const int r1 = r0 | (8 >> gw);
                    cgate(cA[r0], cA[r1], c0r, c0i, c1r, c1i, c2r, c2i, c3r, c3i);
                }
            }

            // scatter (rot4: amp j -> new slot (t<<4)|j), skip after final pass
            if (pp < 14) {
                #pragma unroll
                for (int k = 0; k < 4; ++k) {
                    __half2 h0 = __floats2half2_rn(cA[4*k + 0].x, cA[4*k + 0].y);
                    __half2 h1 = __floats2half2_rn(cA[4*k + 1].x, cA[4*k + 1].y);
                    __half2 h2 = __floats2half2_rn(cA[4*k + 2].x, cA[4*k + 2].y);
                    __half2 h3 = __floats2half2_rn(cA[4*k + 3].x, cA[4*k + 3].y);
                    u4 vv;
                    vv.x = *(unsigned int*)&h0;  vv.y = *(unsigned int*)&h1;
                    vv.z = *(unsigned int*)&h2;  vv.w = *(unsigned int*)&h3;
                    *(u4*)&bufW[wb ^ (k << 2)] = vv;
                }
                __syncthreads();
            }
        }
    }

    // ---- measurement from registers: lane t register j holds amp v=(t<<4)|j ----
    // wire 0 <-> t7, wire 1 <-> t6, wires 2..7 <-> t5..t0, wires 8..11 <-> j3..j0
    float zt = 0.f, z8 = 0.f, z9 = 0.f, z10 = 0.f, z11 = 0.f;
    #pragma unroll
    for (int j = 0; j < 16; ++j) {
        const f2 a = cA[j];
        const float pv = fmaf(a.x, a.x, a.y * a.y);
        zt  += pv;
        z8  += (j & 8) ? -pv : pv;
        z9  += (j & 4) ? -pv : pv;
        z10 += (j & 2) ? -pv : pv;
        z11 += (j & 1) ? -pv : pv;
    }
    const int l = t & 63, wv = t >> 6;
    float R[NQ];
    R[0] = wred(zt);                                   // per-wave total (signs at combine)
    #pragma unroll
    for (int q = 2; q < 8; ++q)
        R[q] = wred(((l >> (7 - q)) & 1) ? -zt : zt);
    R[8] = wred(z8); R[9] = wred(z9); R[10] = wred(z10); R[11] = wred(z11);
    if (l == 0) {
        sRed[wv][0] = R[0];
        #pragma unroll
        for (int q = 2; q < 12; ++q) sRed[wv][q] = R[q];
    }
    __syncthreads();
    if (t < NQ) {
        float v;
        if (t >= 2)      v = sRed[0][t] + sRed[1][t] + sRed[2][t] + sRed[3][t];
        else if (t == 0) v = sRed[0][0] + sRed[1][0] - sRed[2][0] - sRed[3][0];  // w-bit1
        else             v = sRed[0][0] - sRed[1][0] + sRed[2][0] - sRed[3][0];  // w-bit0
        out[(size_t)b * NQ + t] = v;
    }
}

extern "C" void kernel_launch(void* const* d_in, const int* in_sizes, int n_in,
                              void* d_out, int out_size, void* d_ws, size_t ws_size,
                              hipStream_t stream) {
    const float* x    = (const float*)d_in[0];
    const float* Wp   = (const float*)d_in[1];
    const float* bp   = (const float*)d_in[2];
    const float* w    = (const float*)d_in[3];
    const float* scal = (const float*)d_in[4];
    float* outp = (float*)d_out;
    hipLaunchKernelGGL(qsim_kernel, dim3(4096), dim3(256), 0, stream,
                       x, Wp, bp, w, scal, outp);
}

// Round 9
// 153.706 us; speedup vs baseline: 1.7997x; 1.4917x over previous
//
#include <hip/hip_runtime.h>
#include <hip/hip_fp16.h>
#include <math.h>

#define NQ    12
#define PI_F  3.14159265358979f
#define PITCH 1040   // bytes per 16-col tile in B-fragment order (1024 data + 16 pad)

typedef _Float16 h2 __attribute__((ext_vector_type(2)));
typedef _Float16 h8 __attribute__((ext_vector_type(8)));
typedef float f32x4 __attribute__((ext_vector_type(4)));
typedef unsigned int ui4 __attribute__((ext_vector_type(4)));

__device__ __forceinline__ float wred(float v) {
    v += __shfl_xor(v, 1);  v += __shfl_xor(v, 2);  v += __shfl_xor(v, 4);
    v += __shfl_xor(v, 8);  v += __shfl_xor(v, 16); v += __shfl_xor(v, 32);
    return v;
}

// Build this lane's split-precision A fragments for one pass, in registers.
// Lane l (= t&63): row m = l&15, k-slots kk = 4*(l>>4)+u, u=0..3.
// U16[m][kk] = G0[m3][kk3]*G1[m2][kk2]*G2[m1][kk1]*G3[m0][kk0]; kk=(g<<2)|u.
// Fragment slot u (u32 = 2 f16): Ar = {ar, -ai}, Ai = {ai, ar}; hi/lo split.
__device__ __forceinline__ void buildA(const float (*Us)[8], int pt, int lm, int g,
                                       h8 &Arh, h8 &Arl, h8 &Aih, h8 &Ail)
{
    const float* G0 = Us[4 * pt + 0];
    const float* G1 = Us[4 * pt + 1];
    const float* G2 = Us[4 * pt + 2];
    const float* G3 = Us[4 * pt + 3];
    const float* e0 = &G0[((lm >> 3) & 1) * 4 + ((g >> 1) & 1) * 2];
    const float* e1 = &G1[((lm >> 2) & 1) * 4 + (g & 1) * 2];
    const float Pr = e0[0] * e1[0] - e0[1] * e1[1];
    const float Pi = e0[0] * e1[1] + e0[1] * e1[0];
    const float* g2 = &G2[((lm >> 1) & 1) * 4];
    const float T0r = Pr * g2[0] - Pi * g2[1], T0i = Pr * g2[1] + Pi * g2[0];
    const float T1r = Pr * g2[2] - Pi * g2[3], T1i = Pr * g2[3] + Pi * g2[2];
    const float* g3 = &G3[(lm & 1) * 4];
    float er[4], ei[4];
    er[0] = T0r * g3[0] - T0i * g3[1];  ei[0] = T0r * g3[1] + T0i * g3[0];
    er[1] = T0r * g3[2] - T0i * g3[3];  ei[1] = T0r * g3[3] + T0i * g3[2];
    er[2] = T1r * g3[0] - T1i * g3[1];  ei[2] = T1r * g3[1] + T1i * g3[0];
    er[3] = T1r * g3[2] - T1i * g3[3];  ei[3] = T1r * g3[3] + T1i * g3[2];
    #pragma unroll
    for (int u = 0; u < 4; ++u) {
        const _Float16 rh = (_Float16)er[u];
        const _Float16 rl = (_Float16)(er[u] - (float)rh);
        const _Float16 ih = (_Float16)ei[u];
        const _Float16 il = (_Float16)(ei[u] - (float)ih);
        Arh[2*u] = rh;  Arh[2*u + 1] = -ih;
        Arl[2*u] = rl;  Arl[2*u + 1] = -il;
        Aih[2*u] = ih;  Aih[2*u + 1] = rh;
        Ail[2*u] = il;  Ail[2*u + 1] = rl;
    }
}

extern "C" __global__ void __launch_bounds__(256, 4)
qsim_kernel(const float* __restrict__ x, const float* __restrict__ Wp,
            const float* __restrict__ bp, const float* __restrict__ w,
            const float* __restrict__ scal, float* __restrict__ out)
{
    // State in MFMA B-fragment order, ping-pong. Tile tau (16 cols): lane l holds
    // 8 f16 at tau*PITCH + l*16: u32 slot u = pack(Sr[k],Si[k]), k = 4*(l>>4)+u,
    // col n = l&15.
    __shared__ __align__(16) unsigned char sS[2][16 * PITCH];
    __shared__ float sU[5][NQ][8];   // fused per-wire 2x2: {r00,i00,r01,i01,r10,i10,r11,i11}
    __shared__ float sXq[NQ];
    __shared__ float sRed[4][NQ];

    const int t  = threadIdx.x;
    const int b  = blockIdx.x;
    const int l  = t & 63, wv = t >> 6;
    const int g  = l >> 4, lm = l & 15;

    // ---- init state buffer 0 = |0...0> (amp 0: tile 0, lane 0, slot 0) ----
    {
        ui4* s0 = (ui4*)sS[0];
        const ui4 z = {0u, 0u, 0u, 0u};
        #pragma unroll
        for (int k = 0; k < 4; ++k) s0[t + (k << 8)] = z;
        if (t < 16) s0[1024 + t] = z;
        if (t == 0) *(unsigned int*)sS[0] = 0x00003C00u;   // f16 {1.0, 0.0}
    }

    // ---- projection: xq[q] = tanh(x.W[q] + b[q]) * pi ----
    {
        const int q = t >> 4, h = t & 15;
        if (q < NQ) {
            const float* xr = x + (size_t)b * 256;
            const float* wr = Wp + q * 256;
            float acc = 0.f;
            #pragma unroll
            for (int m2 = 0; m2 < 16; ++m2) {
                const int f = h + (m2 << 4);
                acc = fmaf(xr[f], wr[f], acc);
            }
            acc += __shfl_xor(acc, 1);
            acc += __shfl_xor(acc, 2);
            acc += __shfl_xor(acc, 4);
            acc += __shfl_xor(acc, 8);
            if (h == 0) sXq[q] = tanhf(acc + bp[q]) * PI_F;
        }
    }
    __syncthreads();

    // ---- build 60 fused per-wire 2x2 unitaries (f32, plain layout) ----
    if (t < 60) {
        const int s_ = t / 12, q = t - s_ * 12;
        float U[8];
        if (s_ == 4) {
            float c, s; sincosf(0.5f * w[144 + q], &s, &c);
            U[0] = c;  U[1] = 0.f; U[2] = -s; U[3] = 0.f;
            U[4] = s;  U[5] = 0.f; U[6] = c;  U[7] = 0.f;
        } else {
            const float sc = scal[s_];
            const float hx = 0.5f * sc * w[s_ * 36 + q];
            const float hy = 0.5f * sc * w[s_ * 36 + 12 + q];
            const float hz = 0.5f * sc * w[s_ * 36 + 24 + q];
            float cx, sx, cy, sy, cz, sz;
            sincosf(hx, &sx, &cx); sincosf(hy, &sy, &cy); sincosf(hz, &sz, &cz);
            const float T00r = cy * cx, T00i =  sy * sx;
            const float T01r = -sy * cx, T01i = -cy * sx;
            const float T10r =  sy * cx, T10i = -cy * sx;
            const float T11r =  cy * cx, T11i = -sy * sx;
            U[0] = cz * T00r + sz * T00i;  U[1] = cz * T00i - sz * T00r;
            U[2] = cz * T01r + sz * T01i;  U[3] = cz * T01i - sz * T01r;
            U[4] = cz * T10r - sz * T10i;  U[5] = cz * T10i + sz * T10r;
            U[6] = cz * T11r - sz * T11i;  U[7] = cz * T11i + sz * T11r;
            if (s_ == 0) {   // right-multiply by encoding RY (applied first)
                float nrm = 1e-10f;
                #pragma unroll
                for (int k2 = 0; k2 < NQ; ++k2) nrm += sXq[k2] * sXq[k2];
                const float einv = PI_F * rsqrtf(nrm);
                float ce, se; sincosf(0.5f * sXq[q] * einv, &se, &ce);
                const float r00 = U[0]*ce + U[2]*se, i00 = U[1]*ce + U[3]*se;
                const float r01 = U[2]*ce - U[0]*se, i01 = U[3]*ce - U[1]*se;
                const float r10 = U[4]*ce + U[6]*se, i10 = U[5]*ce + U[7]*se;
                const float r11 = U[6]*ce - U[4]*se, i11 = U[7]*ce - U[5]*se;
                U[0]=r00; U[1]=i00; U[2]=r01; U[3]=i01;
                U[4]=r10; U[5]=i10; U[6]=r11; U[7]=i11;
            }
        }
        float* d = sU[s_][q];
        #pragma unroll
        for (int k = 0; k < 8; ++k) d[k] = U[k];
    }
    // prefix-xor of the lane's col-part, hoisted (chain passes)
    int Pl;
    { int wl = lm << 4; Pl = wl ^ (wl >> 1); Pl ^= Pl >> 2; Pl ^= Pl >> 4; Pl ^= Pl >> 8; }
    __syncthreads();

    const f32x4 zero4 = {0.f, 0.f, 0.f, 0.f};

    // ---- 14 MFMA passes with writes; pass 14 peeled (measured from registers) ----
    for (int p = 0; p < 14; ++p) {
        const int cur = p & 1;
        const unsigned char* Sb = sS[cur];
        unsigned char*       Sn = sS[cur ^ 1];

        const int sn = (p * 11) >> 5, pt = p - 3 * sn;   // sweep, part
        h8 Arh, Arl, Aih, Ail;
        buildA(sU[sn], pt, lm, g, Arh, Arl, Aih, Ail);

        unsigned int q[4][4];
        #pragma unroll
        for (int i = 0; i < 4; ++i) {
            const int tau = (wv << 2) | i;
            const h8 B = *(const h8*)(Sb + tau * PITCH + (l << 4));
            f32x4 dr = __builtin_amdgcn_mfma_f32_16x16x32_f16(Arh, B, zero4, 0, 0, 0);
            dr = __builtin_amdgcn_mfma_f32_16x16x32_f16(Arl, B, dr, 0, 0, 0);
            f32x4 di = __builtin_amdgcn_mfma_f32_16x16x32_f16(Aih, B, zero4, 0, 0, 0);
            di = __builtin_amdgcn_mfma_f32_16x16x32_f16(Ail, B, di, 0, 0, 0);
            #pragma unroll
            for (int r = 0; r < 4; ++r) {
                const h2 hp = { (_Float16)dr[r], (_Float16)di[r] };
                q[i][r] = __builtin_bit_cast(unsigned int, hp);
            }
        }

        // scatter to next buffer (rot4 relabel fused into the fragment addressing)
        if (p % 3 == 2) {
            // CNOT-chain pass: producer-side prefix-xor permutation, b32 writes
            #pragma unroll
            for (int i = 0; i < 4; ++i) {
                const int tau = (wv << 2) | i;
                int wt = tau << 8;
                int Pt = wt ^ (wt >> 1); Pt ^= Pt >> 2; Pt ^= Pt >> 4; Pt ^= Pt >> 8;
                #pragma unroll
                for (int r = 0; r < 4; ++r) {
                    const int m  = (g << 2) | r;
                    const int pm = m ^ (m >> 1) ^ (m >> 2) ^ (m >> 3);
                    const int v  = Pt ^ Pl ^ pm;               // standard-order dest index
                    const int k  = v >> 8, tt = (v >> 4) & 15, nn = v & 15;
                    *(unsigned int*)(Sn + tt * PITCH + ((((k >> 2) << 4) | nn) << 4)
                                     + ((k & 3) << 2)) = q[i][r];
                }
            }
        } else {
            // plain rot4: 4 contiguous b128 writes (tiles share dest 16B block)
            #pragma unroll
            for (int r = 0; r < 4; ++r) {
                const ui4 val = { q[0][r], q[1][r], q[2][r], q[3][r] };
                *(ui4*)(Sn + lm * PITCH + (((wv << 4) | (g << 2) | r) << 4)) = val;
            }
        }
        __syncthreads();
    }

    // ---- peeled pass 14 (sweep 4 part 2) + in-register measurement ----
    // Layout: wires 8..11 <-> m bits, wires 0..3 <-> tau bits, wires 4..7 <-> (l&15) bits
    float zt = 0.f, z2 = 0.f, z3 = 0.f, z10 = 0.f, z11 = 0.f;
    {
        h8 Arh, Arl, Aih, Ail;
        buildA(sU[4], 2, lm, g, Arh, Arl, Aih, Ail);
        #pragma unroll
        for (int i = 0; i < 4; ++i) {
            const int tau = (wv << 2) | i;
            const h8 B = *(const h8*)(sS[0] + tau * PITCH + (l << 4));
            f32x4 dr = __builtin_amdgcn_mfma_f32_16x16x32_f16(Arh, B, zero4, 0, 0, 0);
            dr = __builtin_amdgcn_mfma_f32_16x16x32_f16(Arl, B, dr, 0, 0, 0);
            f32x4 di = __builtin_amdgcn_mfma_f32_16x16x32_f16(Aih, B, zero4, 0, 0, 0);
            di = __builtin_amdgcn_mfma_f32_16x16x32_f16(Ail, B, di, 0, 0, 0);
            #pragma unroll
            for (int r = 0; r < 4; ++r) {
                const float pv = dr[r] * dr[r] + di[r] * di[r];
                zt  += pv;
                z2  += (i & 2) ? -pv : pv;   // wire 2 (tau bit 1)
                z3  += (i & 1) ? -pv : pv;   // wire 3 (tau bit 0)
                z10 += (r & 2) ? -pv : pv;   // wire 10 (m bit 1)
                z11 += (r & 1) ? -pv : pv;   // wire 11 (m bit 0)
            }
        }
    }
    float R[NQ];
    R[0]  = wred(zt);                       // wave-level; wire0/1 signs applied at combine
    R[1]  = 0.f;
    R[2]  = wred(z2);
    R[3]  = wred(z3);
    R[4]  = wred((l & 8)  ? -zt : zt);      // wire 4  <-> (l>>3)&1
    R[5]  = wred((l & 4)  ? -zt : zt);
    R[6]  = wred((l & 2)  ? -zt : zt);
    R[7]  = wred((l & 1)  ? -zt : zt);
    R[8]  = wred((l & 32) ? -zt : zt);      // wire 8  <-> g>>1
    R[9]  = wred((l & 16) ? -zt : zt);      // wire 9  <-> g&1
    R[10] = wred(z10);
    R[11] = wred(z11);
    if (l == 0) {
        #pragma unroll
        for (int q2 = 0; q2 < NQ; ++q2) sRed[wv][q2] = R[q2];
    }
    __syncthreads();
    if (t < NQ) {
        float v;
        if (t >= 2)      v = sRed[0][t] + sRed[1][t] + sRed[2][t] + sRed[3][t];
        else if (t == 0) v = sRed[0][0] + sRed[1][0] - sRed[2][0] - sRed[3][0];  // wire0: wv>>1
        else             v = sRed[0][0] - sRed[1][0] + sRed[2][0] - sRed[3][0];  // wire1: wv&1
        out[(size_t)b * NQ + t] = v;
    }
}

extern "C" void kernel_launch(void* const* d_in, const int* in_sizes, int n_in,
                              void* d_out, int out_size, void* d_ws, size_t ws_size,
                              hipStream_t stream) {
    const float* x    = (const float*)d_in[0];
    const float* Wp   = (const float*)d_in[1];
    const float* bp   = (const float*)d_in[2];
    const float* w    = (const float*)d_in[3];
    const float* scal = (const float*)d_in[4];
    float* outp = (float*)d_out;
    hipLaunchKernelGGL(qsim_kernel, dim3(4096), dim3(256), 0, stream,
                       x, Wp, bp, w, scal, outp);
}